// Round 1
// baseline (254.973 us; speedup 1.0000x reference)
//
#include <hip/hip_runtime.h>

#define ALPHA 0.5f
#define NB 4096
#define NC 10000
#define ND 256

// ---------------------------------------------------------------------------
// Kernel 1: scan one-hot matrix [NB, NC], recover labels[b] and counts[c].
// Perfectly coalesced float4 reads; only the (rare) nonzero lane does the
// div/mod + atomic. This kernel carries the traffic floor (163.8 MB).
// ---------------------------------------------------------------------------
__global__ void extract_labels_kernel(const float* __restrict__ onehot,
                                      int* __restrict__ labels,
                                      int* __restrict__ counts) {
    const int total4 = NB * NC / 4;  // 10,240,000 float4s
    int f = blockIdx.x * blockDim.x + threadIdx.x;
    if (f >= total4) return;
    float4 v = reinterpret_cast<const float4*>(onehot)[f];
    float vals[4] = {v.x, v.y, v.z, v.w};
#pragma unroll
    for (int j = 0; j < 4; ++j) {
        if (vals[j] != 0.0f) {
            int e = f * 4 + j;       // max 40,959,999 < 2^31
            int b = e / NC;
            int c = e - b * NC;
            labels[b] = c;
            atomicAdd(&counts[c], 1);
        }
    }
}

// ---------------------------------------------------------------------------
// Kernel 2: one wave (64 lanes) per sample. lane holds float4 (4 of D=256).
//   - loss[b] = sum_d (features[b,d] - centers[label[b],d])^2
//   - S[label[b], :] += features[b, :]   (scatter-add, low contention)
// Block = 256 threads = 4 waves = 4 samples.
// ---------------------------------------------------------------------------
__global__ void per_sample_kernel(const float* __restrict__ features,
                                  const float* __restrict__ centers,
                                  const int* __restrict__ labels,
                                  float* __restrict__ S,      // [NC, ND], zeroed
                                  float* __restrict__ loss) { // [NB]
    const int wave = threadIdx.x >> 6;
    const int lane = threadIdx.x & 63;
    const int b = blockIdx.x * 4 + wave;
    if (b >= NB) return;
    const int c = labels[b];

    const float4 f4 = reinterpret_cast<const float4*>(features + (size_t)b * ND)[lane];
    const float4 c4 = reinterpret_cast<const float4*>(centers + (size_t)c * ND)[lane];

    float dx = f4.x - c4.x;
    float dy = f4.y - c4.y;
    float dz = f4.z - c4.z;
    float dw = f4.w - c4.w;
    float s = dx * dx + dy * dy + dz * dz + dw * dw;

    // wave-64 reduction
#pragma unroll
    for (int off = 32; off > 0; off >>= 1)
        s += __shfl_down(s, off, 64);

    // scatter features into per-class sum
    float* Sp = S + (size_t)c * ND + lane * 4;
    atomicAdd(Sp + 0, f4.x);
    atomicAdd(Sp + 1, f4.y);
    atomicAdd(Sp + 2, f4.z);
    atomicAdd(Sp + 3, f4.w);

    if (lane == 0) loss[b] = s;
}

// ---------------------------------------------------------------------------
// Kernel 3: new_centers = centers - ALPHA * (cnt*centers - S) / (cnt + 1)
// Elementwise over [NC, ND] as float4.
// ---------------------------------------------------------------------------
__global__ void update_centers_kernel(const float* __restrict__ centers,
                                      const float* __restrict__ S,
                                      const int* __restrict__ counts,
                                      float* __restrict__ out) { // [NC, ND]
    const int total4 = NC * ND / 4;  // 640,000
    int idx = blockIdx.x * blockDim.x + threadIdx.x;
    if (idx >= total4) return;
    const int c = idx / (ND / 4);  // idx / 64
    const float cnt = (float)counts[c];
    const float scale = ALPHA / (cnt + 1.0f);

    float4 ce = reinterpret_cast<const float4*>(centers)[idx];
    float4 s4 = reinterpret_cast<const float4*>(S)[idx];
    float4 o;
    o.x = ce.x - (cnt * ce.x - s4.x) * scale;
    o.y = ce.y - (cnt * ce.y - s4.y) * scale;
    o.z = ce.z - (cnt * ce.z - s4.z) * scale;
    o.w = ce.w - (cnt * ce.w - s4.w) * scale;
    reinterpret_cast<float4*>(out)[idx] = o;
}

extern "C" void kernel_launch(void* const* d_in, const int* in_sizes, int n_in,
                              void* d_out, int out_size, void* d_ws, size_t ws_size,
                              hipStream_t stream) {
    const float* features = (const float*)d_in[0];  // [4096, 256]
    const float* onehot   = (const float*)d_in[1];  // [4096, 10000]
    const float* centers  = (const float*)d_in[2];  // [10000, 256]

    // Output layout: loss [4096] then new_centers [10000*256], flat.
    float* loss        = (float*)d_out;
    float* new_centers = (float*)d_out + NB;

    // Workspace layout (ws is re-poisoned to 0xAA each call — zero what we use):
    //   labels : NB ints      (written fully by kernel 1, no zeroing needed)
    //   counts : NC ints      (must be zeroed)
    //   S      : NC*ND floats (must be zeroed)
    int*   labels = (int*)d_ws;
    int*   counts = labels + NB;
    float* S      = (float*)(counts + NC);  // offset (NB+NC)*4 = 56384 B, 16B-aligned

    hipMemsetAsync(counts, 0, NC * sizeof(int), stream);
    hipMemsetAsync(S, 0, (size_t)NC * ND * sizeof(float), stream);

    {
        int total4 = NB * NC / 4;
        int blocks = (total4 + 255) / 256;
        extract_labels_kernel<<<blocks, 256, 0, stream>>>(onehot, labels, counts);
    }
    per_sample_kernel<<<NB / 4, 256, 0, stream>>>(features, centers, labels, S, loss);
    {
        int total4 = NC * ND / 4;
        int blocks = (total4 + 255) / 256;
        update_centers_kernel<<<blocks, 256, 0, stream>>>(centers, S, counts, new_centers);
    }
}

// Round 2
// 252.386 us; speedup vs baseline: 1.0103x; 1.0103x over previous
//
#include <hip/hip_runtime.h>

#define ALPHA 0.5f
#define NB 4096
#define NC 10000
#define ND 256

// ---------------------------------------------------------------------------
// Kernel 1: scan one-hot [NB, NC]; recover labels[b], counts[c].
// Coalesced float4 reads; only the rare nonzero lane does div + atomic.
// Carries the traffic floor (163.84 MB read).
// ---------------------------------------------------------------------------
__global__ void extract_labels_kernel(const float* __restrict__ onehot,
                                      int* __restrict__ labels,
                                      int* __restrict__ counts) {
    const int total4 = NB * NC / 4;  // 10,240,000
    int f = blockIdx.x * blockDim.x + threadIdx.x;
    if (f >= total4) return;
    float4 v = reinterpret_cast<const float4*>(onehot)[f];
    float vals[4] = {v.x, v.y, v.z, v.w};
#pragma unroll
    for (int j = 0; j < 4; ++j) {
        if (vals[j] != 0.0f) {
            int e = f * 4 + j;
            int b = e / NC;
            int c = e - b * NC;
            labels[b] = c;
            atomicAdd(&counts[c], 1);
        }
    }
}

// ---------------------------------------------------------------------------
// Kernel 2: base term of the center update, straight into d_out:
//   new_centers[c,:] = centers[c,:] * (1 - ALPHA*cnt/(cnt+1))
// (classes with cnt==0 copy through unchanged — matches reference).
// The per-sample kernel then atomically adds ALPHA*f/(cnt+1) on top.
// ---------------------------------------------------------------------------
__global__ void scale_centers_kernel(const float* __restrict__ centers,
                                     const int* __restrict__ counts,
                                     float* __restrict__ out) { // [NC, ND]
    const int total4 = NC * ND / 4;  // 640,000
    int idx = blockIdx.x * blockDim.x + threadIdx.x;
    if (idx >= total4) return;
    const int c = idx >> 6;  // ND/4 = 64 float4 per row
    const float cnt = (float)counts[c];
    const float k = 1.0f - ALPHA * cnt / (cnt + 1.0f);

    float4 ce = reinterpret_cast<const float4*>(centers)[idx];
    float4 o = {ce.x * k, ce.y * k, ce.z * k, ce.w * k};
    reinterpret_cast<float4*>(out)[idx] = o;
}

// ---------------------------------------------------------------------------
// Kernel 3: one wave per sample.
//   loss[b] = || features[b] - centers[label[b]] ||^2   (OLD centers)
//   new_centers[label[b],:] += ALPHA/(cnt+1) * features[b,:]  (atomic)
// Block = 256 = 4 waves = 4 samples. Avg 0.41 samples/class -> low contention.
// ---------------------------------------------------------------------------
__global__ void per_sample_kernel(const float* __restrict__ features,
                                  const float* __restrict__ centers,
                                  const int* __restrict__ labels,
                                  const int* __restrict__ counts,
                                  float* __restrict__ new_centers,
                                  float* __restrict__ loss) { // [NB]
    const int wave = threadIdx.x >> 6;
    const int lane = threadIdx.x & 63;
    const int b = blockIdx.x * 4 + wave;
    if (b >= NB) return;
    const int c = labels[b];
    const float scale = ALPHA / ((float)counts[c] + 1.0f);

    const float4 f4 = reinterpret_cast<const float4*>(features + (size_t)b * ND)[lane];
    const float4 c4 = reinterpret_cast<const float4*>(centers + (size_t)c * ND)[lane];

    float dx = f4.x - c4.x;
    float dy = f4.y - c4.y;
    float dz = f4.z - c4.z;
    float dw = f4.w - c4.w;
    float s = dx * dx + dy * dy + dz * dz + dw * dw;

#pragma unroll
    for (int off = 32; off > 0; off >>= 1)
        s += __shfl_down(s, off, 64);

    float* np = new_centers + (size_t)c * ND + lane * 4;
    atomicAdd(np + 0, f4.x * scale);
    atomicAdd(np + 1, f4.y * scale);
    atomicAdd(np + 2, f4.z * scale);
    atomicAdd(np + 3, f4.w * scale);

    if (lane == 0) loss[b] = s;
}

extern "C" void kernel_launch(void* const* d_in, const int* in_sizes, int n_in,
                              void* d_out, int out_size, void* d_ws, size_t ws_size,
                              hipStream_t stream) {
    const float* features = (const float*)d_in[0];  // [4096, 256]
    const float* onehot   = (const float*)d_in[1];  // [4096, 10000]
    const float* centers  = (const float*)d_in[2];  // [10000, 256]

    float* loss        = (float*)d_out;        // [4096]
    float* new_centers = (float*)d_out + NB;   // [10000, 256]

    // Workspace: labels [NB] ints, counts [NC] ints (zeroed). No S buffer.
    int* labels = (int*)d_ws;
    int* counts = labels + NB;

    hipMemsetAsync(counts, 0, NC * sizeof(int), stream);

    {
        int total4 = NB * NC / 4;
        extract_labels_kernel<<<(total4 + 255) / 256, 256, 0, stream>>>(onehot, labels, counts);
    }
    {
        int total4 = NC * ND / 4;
        scale_centers_kernel<<<(total4 + 255) / 256, 256, 0, stream>>>(centers, counts, new_centers);
    }
    per_sample_kernel<<<NB / 4, 256, 0, stream>>>(features, centers, labels, counts,
                                                  new_centers, loss);
}